// Round 1
// baseline (423.574 us; speedup 1.0000x reference)
//
#include <hip/hip_runtime.h>

#define DIM 4096

// XOR swizzle on float index: banks spread for all three access patterns,
// preserves float4 (16B) alignment since bits 0,1 are untouched.
__device__ __forceinline__ int swz(int i) {
    return i ^ (((i >> 6) & 15) << 2);
}

// In-place natural-order H16 (4 butterfly stages) on 16 registers.
__device__ __forceinline__ void h16(float v[16]) {
#pragma unroll
    for (int h = 1; h < 16; h <<= 1) {
#pragma unroll
        for (int i = 0; i < 16; i += 2 * h) {
#pragma unroll
            for (int j = i; j < i + h; ++j) {
                float a = v[j], b = v[j + h];
                v[j] = a + b;
                v[j + h] = a - b;
            }
        }
    }
}

// One 4096-float row per block of 256 threads.
// H4096 = product of 12 commuting H2 factors (one per index bit).
// Pass A: bits {0,1,10,11} (register H16 after coalesced float4 loads)
// Pass B: bits {2,3,4,5}   (LDS gather, register H16)
// Pass C: bits {6,7,8,9}   (LDS gather, register H16, coalesced store)
extern "C" __global__ __launch_bounds__(256)
void fwht4096(const float* __restrict__ x, float* __restrict__ out) {
    __shared__ float lds[DIM];
    const size_t row = blockIdx.x;
    const float* __restrict__ xr = x + row * (size_t)DIM;
    float* __restrict__ yr = out + row * (size_t)DIM;
    const int u = threadIdx.x;
    float v[16];

    // ---- Pass A: thread u holds i = m*1024 + 4u + r  (local idx = m*4 + r)
    const float4* x4 = (const float4*)xr;
    float4 a0 = x4[u];
    float4 a1 = x4[u + 256];
    float4 a2 = x4[u + 512];
    float4 a3 = x4[u + 768];
    v[0] = a0.x;  v[1] = a0.y;  v[2] = a0.z;  v[3] = a0.w;
    v[4] = a1.x;  v[5] = a1.y;  v[6] = a1.z;  v[7] = a1.w;
    v[8] = a2.x;  v[9] = a2.y;  v[10] = a2.z; v[11] = a2.w;
    v[12] = a3.x; v[13] = a3.y; v[14] = a3.z; v[15] = a3.w;
    h16(v);

#pragma unroll
    for (int m = 0; m < 4; ++m) {
        int la = swz(m * 1024 + 4 * u);   // contiguous & 16B aligned after swizzle
        *(float4*)&lds[la] = make_float4(v[4 * m], v[4 * m + 1], v[4 * m + 2], v[4 * m + 3]);
    }
    __syncthreads();

    // ---- Pass B: bits {2..5}. Thread bits: {0,1}=u&3, {6..9}=(u>>2)&15, {10,11}=u>>6.
    {
        const int base = (u & 3) | (((u >> 2) & 15) << 6) | ((u >> 6) << 10);
#pragma unroll
        for (int n = 0; n < 16; ++n) v[n] = lds[swz(base + (n << 2))];
        h16(v);
        // read/write set is a per-thread bijection -> no barrier needed between them
#pragma unroll
        for (int n = 0; n < 16; ++n) lds[swz(base + (n << 2))] = v[n];
    }
    __syncthreads();

    // ---- Pass C: bits {6..9}. Thread bits: {0..5}=u&63, {10,11}=u>>6.
    {
        const int base = (u & 63) | ((u >> 6) << 10);
#pragma unroll
        for (int c = 0; c < 16; ++c) v[c] = lds[swz(base + (c << 6))];
        h16(v);
        const float s = 0.015625f;  // 1/sqrt(4096)
#pragma unroll
        for (int c = 0; c < 16; ++c) yr[base + (c << 6)] = v[c] * s;  // lane-consecutive dwords
    }
}

extern "C" void kernel_launch(void* const* d_in, const int* in_sizes, int n_in,
                              void* d_out, int out_size, void* d_ws, size_t ws_size,
                              hipStream_t stream) {
    const float* x = (const float*)d_in[0];
    float* out = (float*)d_out;
    const int rows = out_size / DIM;  // 8*2048 = 16384
    fwht4096<<<rows, 256, 0, stream>>>(x, out);
}